// Round 9
// baseline (1182.444 us; speedup 1.0000x reference)
//
#include <hip/hip_runtime.h>
#include <stdint.h>

#define TSTEPS 2048
#define L2E  1.4426950408889634f
#define TABN 2048
#define TABS 102.4f           // TABN / 20  -> sigma domain [-10, 10)
#define TABC 1024.0f          // center index

typedef _Float16 half8 __attribute__((ext_vector_type(8)));
typedef float    f32x4 __attribute__((ext_vector_type(4)));

// Interpolated sigma lookup. y is ALREADY the table index (the MFMA weights
// carry the *TABS scaling and the bias carries +TABC, so the accumulator is
// the index). ~7 full-rate VALU ops + 1 ds_read2_b32 -- replaces an exp+rcp
// pair on the ~20-25 cyc/op trans pipe.
__device__ __forceinline__ float lut(const float* __restrict__ t, float y) {
    y = __builtin_amdgcn_fmed3f(y, 0.0f, 2046.99f);   // clamp to [0, TABN-2]
    float fl = truncf(y);
    float fr = y - fl;
    int   i  = (int)fl;
    float v0 = t[i];
    float v1 = t[i + 1];
    return fmaf(fr, v1 - v0, v0);
}

// 4 independent waves per 256-thread WG; each wave owns 2 batch sequences
// -> 4096 waves = 4/SIMD. Per wave-step: 8 VALU FMAs init acc[n][0], 8x
// mfma_f32_16x16x32_f16 with 8x-row-duplicated A (A[m]=h[batch m>>3]).
// D mapping (m89-verified: row=(lane>>4)*4+r, col=lane&15): elem 0 of
// acc[2t+p] = gate t of cell (batch=quad>>1, unit=cidx+16p), p=quad&1.
// Unused acc rows accumulate bounded garbage (fp32, never read).
//
// Activations via shared sigma LUT: si=LUT(yi), sf=LUT(yf), tanh(g)=
// 2*LUT(yg)-1 (g-weights carry 2*TABS), tanh(c)=2*LUT(c*2*TABS+TABC)-1.
// c' = sf*c + si*tg; h = so*tc. Zero trans ops in the loop.
//
// h feedback: 128 B/wave f16 LDS slice, write addr == lane, read b128 at
// (cidx>>3)*64+quad*16. Same-wave DS ops are in-order; compiler-only
// barrier keeps write->read program order (r8-verified).
extern "C" __global__ void __launch_bounds__(256, 4)
lstm_lut(const float* __restrict__ x,     // [B, T]
         const float* __restrict__ W_ih,  // [128]
         const float* __restrict__ W_hh,  // [128, 32]
         const float* __restrict__ b_ih,  // [128]
         const float* __restrict__ b_hh,  // [128]
         const float* __restrict__ W3,    // [32, 32]
         const float* __restrict__ b3,    // [32]
         const float* __restrict__ W4,    // [32]
         const float* __restrict__ b4,    // [1]
         float* __restrict__ out)         // [B]
{
    const int tid  = threadIdx.x;
    const int wid  = tid >> 6;             // wave 0..3 (independent)
    const int lane = tid & 63;
    const int cidx = lane & 15;
    const int quad = lane >> 4;
    const bool ph  = (quad & 1) != 0;      // unit-half selector
    const int myb  = quad >> 1;            // this lane's batch (0/1)
    const int wb   = blockIdx.x * 8 + wid * 2;

    __shared__ float    stab[TABN + 4];    // sigma table, WG-shared
    __shared__ _Float16 hsh[4][64];        // per-wave h[2][32]

    // ---- fill sigma table: stab[i] = sigma((i-TABC)/TABS) ----
    for (int i = tid; i < TABN + 4; i += 256) {
        float xv = ((float)i - TABC) * (1.0f / TABS);   // 1/TABS exact
        stab[i] = 1.0f / (1.0f + __expf(-xv));
    }

    // ---- loop-invariant fragments (index scaling folded in) ----
    // tiles 0,1=i 2,3=f 4,5=g 6,7=o; g rows get 2*TABS (tanh via 2sig-1)
    half8 bfrag[8];
    float wihs[8], biass[8];
    #pragma unroll
    for (int n = 0; n < 8; ++n) {
        const int g = 16 * n + cidx;
        const float s = (n == 4 || n == 5) ? (2.0f * TABS) : TABS;
        const float* wr = W_hh + g * 32 + quad * 8;
        float4 w0 = *(const float4*)(wr);
        float4 w1 = *(const float4*)(wr + 4);
        half8 hb;
        hb[0] = (_Float16)(w0.x * s); hb[1] = (_Float16)(w0.y * s);
        hb[2] = (_Float16)(w0.z * s); hb[3] = (_Float16)(w0.w * s);
        hb[4] = (_Float16)(w1.x * s); hb[5] = (_Float16)(w1.y * s);
        hb[6] = (_Float16)(w1.z * s); hb[7] = (_Float16)(w1.w * s);
        bfrag[n] = hb;
        wihs[n]  = W_ih[g] * s;
        biass[n] = (b_ih[g] + b_hh[g]) * s + TABC;   // accumulator == index
    }

    float c = 0.0f;
    hsh[wid][lane] = (_Float16)0.0f;
    __syncthreads();                       // table + h ready (once)

    const float* xp = x + (size_t)(wb + myb) * TSTEPS;
    float4 xnext = *(const float4*)(xp);

    f32x4 acc[8];
    #pragma unroll
    for (int n = 0; n < 8; ++n) acc[n] = (f32x4){0.f, 0.f, 0.f, 0.f};

    const char* hb8 = (const char*)&hsh[wid][0];
    const int abyte = (cidx >> 3) * 64 + quad * 16;  // A[m=cidx][k=quad*8+q]

    for (int t0 = 0; t0 < TSTEPS; t0 += 4) {
        float4 xc = xnext;
        if (t0 + 4 < TSTEPS) xnext = *(const float4*)(xp + t0 + 4);
        #pragma unroll
        for (int tt = 0; tt < 4; ++tt) {
            union { uint4 u4; half8 h; } af;
            af.u4 = *(const uint4*)(hb8 + abyte);

            const float xs = ((const float*)&xc)[tt];
            #pragma unroll
            for (int n = 0; n < 8; ++n)
                acc[n][0] = fmaf(xs, wihs[n], biass[n]);

            #pragma unroll
            for (int n = 0; n < 8; ++n)
                acc[n] = __builtin_amdgcn_mfma_f32_16x16x32_f16(
                             af.h, bfrag[n], acc[n], 0, 0, 0);

            // gate indices: tile 2t+p, element 0 (compile-time reg)
            float yi = ph ? acc[1][0] : acc[0][0];
            float yf = ph ? acc[3][0] : acc[2][0];
            float yg = ph ? acc[5][0] : acc[4][0];
            float yo = ph ? acc[7][0] : acc[6][0];

            float si = lut(stab, yi);
            float sf = lut(stab, yf);
            float tg = fmaf(2.0f, lut(stab, yg), -1.0f);   // tanh(g)
            float so = lut(stab, yo);
            c = fmaf(sf, c, si * tg);
            float tc = fmaf(2.0f, lut(stab, fmaf(c, 2.0f * TABS, TABC)),
                            -1.0f);                         // tanh(c)
            hsh[wid][lane] = (_Float16)(so * tc);
            asm volatile("" ::: "memory");   // keep write->read order
        }
    }

    // ---- head: 2 batches/wave; lane j=lane&31 (unit), g0=lane>>5 (batch)
    const int j  = lane & 31;
    const int g0 = lane >> 5;
    float a = b3[j];
    #pragma unroll
    for (int k = 0; k < 32; ++k)
        a = fmaf((float)hsh[wid][g0 * 32 + k], W3[j * 32 + k], a);
    a = fmaxf(a, 0.0f);
    float v = a * W4[j];
    #pragma unroll
    for (int off = 16; off >= 1; off >>= 1)   // stays within 32-lane halves
        v += __shfl_xor(v, off);
    if ((lane & 31) == 0) {
        float e = __builtin_amdgcn_exp2f(-(v + b4[0]) * L2E);
        out[wb + g0] = __builtin_amdgcn_rcpf(1.0f + e);
    }
}

extern "C" void kernel_launch(void* const* d_in, const int* in_sizes, int n_in,
                              void* d_out, int out_size, void* d_ws, size_t ws_size,
                              hipStream_t stream) {
    const float* x    = (const float*)d_in[0];
    const float* W_ih = (const float*)d_in[1];
    const float* W_hh = (const float*)d_in[2];
    const float* b_ih = (const float*)d_in[3];
    const float* b_hh = (const float*)d_in[4];
    const float* W3   = (const float*)d_in[5];
    const float* b3   = (const float*)d_in[6];
    const float* W4   = (const float*)d_in[7];
    const float* b4   = (const float*)d_in[8];
    float* out = (float*)d_out;

    const int batches = out_size;          // 8192
    const int blocks  = batches / 8;       // 1024 WGs x 4 waves x 2 batches
    lstm_lut<<<blocks, 256, 0, stream>>>(x, W_ih, W_hh, b_ih, b_hh,
                                         W3, b3, W4, b4, out);
}

// Round 10
// 801.200 us; speedup vs baseline: 1.4758x; 1.4758x over previous
//
#include <hip/hip_runtime.h>
#include <stdint.h>

#define TSTEPS 2048
#define L2E 1.4426950408889634f   // log2(e)

typedef _Float16 half8 __attribute__((ext_vector_type(8)));
typedef float    f32x4 __attribute__((ext_vector_type(4)));

// 4 independent waves per 256-thread WG (no barriers); each wave owns 4
// batch sequences -> 2048 waves = 2/SIMD. Rationale (r8/r9 fits): trans
// work per SIMD-step is invariant in B, but MFMA count and per-wave
// overhead scale 1/B -> B=4 halves both vs r8 (B=2).
//
// A is 4x-row-duplicated: A[m] = h[batch m>>2]. D mapping (m89-verified:
// row=(lane>>4)*4+r, col=lane&15): all 4 regs of lane (cidx,quad) belong
// to batch quad; elem 0 of acc[2t+p] = gate t of cell (batch=quad,
// unit=cidx+16p). Lane owns 2 cells (p=0,1) -> two independent activation
// chains (ILP). Unused dup rows: regs 1-3 hold bounded garbage, never read.
//
// Activation (r8-verified, 7 trans/cell = 5 exp2 + 2 rcp, exact algebra,
// weights pre-scaled by -log2e for i,f,o and +2log2e for g):
//   ei=e^-i ef=e^-f eg=e^2g; p1=1+ei p2=1+eg p3=1+ef
//   c' = (c*p1p2 + (eg-1)*p3) * rcp(p3*p1p2)
//   h  = (ec-1) * rcp((1+eo)(1+ec)),  ec = e^{2*clamp(c',+-15)}
//
// h feedback: 256 B/wave f16 LDS slice hsh[wid][batch][unit] (64 B row),
// write 2x u16 (r5-verified conflict-free), read b128 at
// (cidx>>2)*64 + quad*16. Same-wave DS ops are in-order; compiler-only
// barrier keeps write->read program order (r8-verified).
extern "C" __global__ void __launch_bounds__(256, 4)
lstm_b4(const float* __restrict__ x,     // [B, T]
        const float* __restrict__ W_ih,  // [128]
        const float* __restrict__ W_hh,  // [128, 32]
        const float* __restrict__ b_ih,  // [128]
        const float* __restrict__ b_hh,  // [128]
        const float* __restrict__ W3,    // [32, 32]
        const float* __restrict__ b3,    // [32]
        const float* __restrict__ W4,    // [32]
        const float* __restrict__ b4,    // [1]
        float* __restrict__ out)         // [B]
{
    const int tid  = threadIdx.x;
    const int wid  = tid >> 6;             // wave 0..3 (independent)
    const int lane = tid & 63;
    const int cidx = lane & 15;
    const int quad = lane >> 4;            // == this lane's batch (0..3)
    const int wb   = blockIdx.x * 16 + wid * 4;  // 4 batches per wave

    __shared__ _Float16 hsh[4][4 * 32];    // per-wave h[4][32], 256 B

    // ---- loop-invariant fragments ----
    // bfrag[n]: W_hh B-frag, lane holds B[k=quad*8+q][gatecol=16n+cidx]
    half8 bfrag[8];
    float wihs[8], biass[8];
    #pragma unroll
    for (int n = 0; n < 8; ++n) {
        const int g = 16 * n + cidx;
        const float s = (n == 4 || n == 5) ? (2.0f * L2E) : (-L2E);
        const float* wr = W_hh + g * 32 + quad * 8;
        float4 w0 = *(const float4*)(wr);
        float4 w1 = *(const float4*)(wr + 4);
        half8 hb;
        hb[0] = (_Float16)(w0.x * s); hb[1] = (_Float16)(w0.y * s);
        hb[2] = (_Float16)(w0.z * s); hb[3] = (_Float16)(w0.w * s);
        hb[4] = (_Float16)(w1.x * s); hb[5] = (_Float16)(w1.y * s);
        hb[6] = (_Float16)(w1.z * s); hb[7] = (_Float16)(w1.w * s);
        bfrag[n] = hb;
        wihs[n]  = W_ih[g] * s;
        biass[n] = (b_ih[g] + b_hh[g]) * s;
    }

    float c0 = 0.0f, c1 = 0.0f;            // cells (batch quad, units cidx, cidx+16)
    hsh[wid][quad * 32 + cidx]      = (_Float16)0.0f;
    hsh[wid][quad * 32 + 16 + cidx] = (_Float16)0.0f;
    asm volatile("" ::: "memory");

    const float* xp = x + (size_t)(wb + quad) * TSTEPS;
    float4 xnext = *(const float4*)(xp);

    f32x4 acc[8];
    #pragma unroll
    for (int n = 0; n < 8; ++n) acc[n] = (f32x4){0.f, 0.f, 0.f, 0.f};

    const char* hb8 = (const char*)&hsh[wid][0];
    const int abyte = (cidx >> 2) * 64 + quad * 16;  // A[m=cidx][k=quad*8+q]

    for (int t0 = 0; t0 < TSTEPS; t0 += 4) {
        float4 xc = xnext;
        if (t0 + 4 < TSTEPS) xnext = *(const float4*)(xp + t0 + 4);
        #pragma unroll
        for (int tt = 0; tt < 4; ++tt) {
            union { uint4 u4; half8 h; } af;
            af.u4 = *(const uint4*)(hb8 + abyte);

            const float xs = ((const float*)&xc)[tt];
            #pragma unroll
            for (int n = 0; n < 8; ++n)
                acc[n][0] = fmaf(xs, wihs[n], biass[n]);

            #pragma unroll
            for (int n = 0; n < 8; ++n)
                acc[n] = __builtin_amdgcn_mfma_f32_16x16x32_f16(
                             af.h, bfrag[n], acc[n], 0, 0, 0);

            // ---- cell 0: unit cidx (tiles 0,2,4,6) ----
            {
                float ei = __builtin_amdgcn_exp2f(acc[0][0]);
                float ef = __builtin_amdgcn_exp2f(acc[2][0]);
                float eg = __builtin_amdgcn_exp2f(acc[4][0]);
                float p1 = 1.0f + ei, p2 = 1.0f + eg, p3 = 1.0f + ef;
                float q12 = p1 * p2;
                float num = fmaf(c0, q12, (eg - 1.0f) * p3);
                c0 = num * __builtin_amdgcn_rcpf(p3 * q12);
                float cc = __builtin_amdgcn_fmed3f(c0, -15.0f, 15.0f);
                float eo = __builtin_amdgcn_exp2f(acc[6][0]);
                float ec = __builtin_amdgcn_exp2f(cc * (2.0f * L2E));
                float rh = __builtin_amdgcn_rcpf((1.0f + eo) * (1.0f + ec));
                hsh[wid][quad * 32 + cidx] = (_Float16)((ec - 1.0f) * rh);
            }
            // ---- cell 1: unit cidx+16 (tiles 1,3,5,7) ----
            {
                float ei = __builtin_amdgcn_exp2f(acc[1][0]);
                float ef = __builtin_amdgcn_exp2f(acc[3][0]);
                float eg = __builtin_amdgcn_exp2f(acc[5][0]);
                float p1 = 1.0f + ei, p2 = 1.0f + eg, p3 = 1.0f + ef;
                float q12 = p1 * p2;
                float num = fmaf(c1, q12, (eg - 1.0f) * p3);
                c1 = num * __builtin_amdgcn_rcpf(p3 * q12);
                float cc = __builtin_amdgcn_fmed3f(c1, -15.0f, 15.0f);
                float eo = __builtin_amdgcn_exp2f(acc[7][0]);
                float ec = __builtin_amdgcn_exp2f(cc * (2.0f * L2E));
                float rh = __builtin_amdgcn_rcpf((1.0f + eo) * (1.0f + ec));
                hsh[wid][quad * 32 + 16 + cidx] = (_Float16)((ec - 1.0f) * rh);
            }
            asm volatile("" ::: "memory");   // keep write->read order
        }
    }

    // ---- head: 4 batches/wave; j=lane&31 (unit), g0=lane>>5; batches g0, g0+2
    const int j  = lane & 31;
    const int g0 = lane >> 5;
    float a0 = b3[j], a1 = b3[j];
    #pragma unroll
    for (int k = 0; k < 32; ++k) {
        float w3v = W3[j * 32 + k];
        a0 = fmaf((float)hsh[wid][g0 * 32 + k],       w3v, a0);
        a1 = fmaf((float)hsh[wid][(g0 + 2) * 32 + k], w3v, a1);
    }
    a0 = fmaxf(a0, 0.0f);
    a1 = fmaxf(a1, 0.0f);
    const float w4 = W4[j];
    float v0 = a0 * w4, v1 = a1 * w4;
    #pragma unroll
    for (int off = 16; off >= 1; off >>= 1) {  // stays within 32-lane halves
        v0 += __shfl_xor(v0, off);
        v1 += __shfl_xor(v1, off);
    }
    if ((lane & 31) == 0) {
        float e0 = __builtin_amdgcn_exp2f(-(v0 + b4[0]) * L2E);
        float e1 = __builtin_amdgcn_exp2f(-(v1 + b4[0]) * L2E);
        out[wb + g0]     = __builtin_amdgcn_rcpf(1.0f + e0);
        out[wb + g0 + 2] = __builtin_amdgcn_rcpf(1.0f + e1);
    }
}

extern "C" void kernel_launch(void* const* d_in, const int* in_sizes, int n_in,
                              void* d_out, int out_size, void* d_ws, size_t ws_size,
                              hipStream_t stream) {
    const float* x    = (const float*)d_in[0];
    const float* W_ih = (const float*)d_in[1];
    const float* W_hh = (const float*)d_in[2];
    const float* b_ih = (const float*)d_in[3];
    const float* b_hh = (const float*)d_in[4];
    const float* W3   = (const float*)d_in[5];
    const float* b3   = (const float*)d_in[6];
    const float* W4   = (const float*)d_in[7];
    const float* b4   = (const float*)d_in[8];
    float* out = (float*)d_out;

    const int batches = out_size;          // 8192
    const int blocks  = batches / 16;      // 512 WGs x 4 waves x 4 batches
    lstm_b4<<<blocks, 256, 0, stream>>>(x, W_ih, W_hh, b_ih, b_hh,
                                        W3, b3, W4, b4, out);
}